// Round 11
// baseline (180.738 us; speedup 1.0000x reference)
//
#include <hip/hip_runtime.h>
#include <hip/hip_bf16.h>
#include <stdint.h>

#define HID 2048
#define NH  32
#define HD  64
#define NB  8
#define NS  16
#define PAST 4096

// log2(e) / sqrt(D) = 1.4426950408889634 / 8
#define QSCALE 0.18033688011112042591f

typedef __attribute__((ext_vector_type(8))) short short8;
typedef __attribute__((ext_vector_type(4))) short short4v;
typedef __attribute__((ext_vector_type(4))) float f32x4;

#define MFMA(a, b, c) __builtin_amdgcn_mfma_f32_16x16x32_bf16((a), (b), (c), 0, 0, 0)

#define PART_STRIDE 1088  // 16 m + 16 l + 16*64 O + pad, floats
#define NSPLIT 8          // attn splits per (b,h); 512 pos per split
#define MATSZ (128 * HID) // elements of one projection output
#define VP 68             // u16 row stride of V slab (136B = 17x8B, conflict-free reads)
#define WSLAB 4352        // bytes per wave: 2 bufs x 16 x VP x 2B

static __device__ __forceinline__ short f2bf(float f) {
    __hip_bfloat16 h = __float2bfloat16(f);
    return *reinterpret_cast<short*>(&h);
}

static __device__ __forceinline__ short8 pack8(float4 a, float4 b) {
    short8 r;
    r[0] = f2bf(a.x); r[1] = f2bf(a.y); r[2] = f2bf(a.z); r[3] = f2bf(a.w);
    r[4] = f2bf(b.x); r[5] = f2bf(b.y); r[6] = f2bf(b.z); r[7] = f2bf(b.w);
    return r;
}

static __device__ __forceinline__ short4v pack4(float4 a) {
    short4v r;
    r[0] = f2bf(a.x); r[1] = f2bf(a.y); r[2] = f2bf(a.z); r[3] = f2bf(a.w);
    return r;
}

static __device__ __forceinline__ short8 pack8s(float4 a, float4 b, float s) {
    short8 r;
    r[0] = f2bf(a.x * s); r[1] = f2bf(a.y * s); r[2] = f2bf(a.z * s); r[3] = f2bf(a.w * s);
    r[4] = f2bf(b.x * s); r[5] = f2bf(b.y * s); r[6] = f2bf(b.z * s); r[7] = f2bf(b.w * s);
    return r;
}

// ---------------- hidden fp32 -> bf16 ----------------
__global__ __launch_bounds__(256) void cvt_kernel(const float* __restrict__ in,
                                                  short* __restrict__ out) {
    int i = (blockIdx.x * 256 + threadIdx.x) * 4;
    float4 v = *reinterpret_cast<const float4*>(in + i);
    short4v o;
    o[0] = f2bf(v.x); o[1] = f2bf(v.y); o[2] = f2bf(v.z); o[3] = f2bf(v.w);
    *reinterpret_cast<short4v*>(out + i) = o;
}

// ------- Ypart[mat*4+ks] = Xbf16 @ W^T slice (M=128, K-split x4, N=16) -----
__global__ __launch_bounds__(128) void proj_kernel(
        const short* __restrict__ X,
        const float* __restrict__ W0, const float* __restrict__ W1,
        const float* __restrict__ W2,
        float* __restrict__ Yp) {
    int mat   = blockIdx.x >> 9;
    int rest  = blockIdx.x & 511;
    int strip = rest >> 2, ks = rest & 3;
    int nbase = strip * 16;
    int k0    = ks * 512;
    const float* W = (mat == 0) ? W0 : (mat == 1) ? W1 : W2;
    float* Y = Yp + (size_t)(mat * 4 + ks) * MATSZ;

    int lane = threadIdx.x & 63;
    int wave = threadIdx.x >> 6;
    int lr = lane & 15, g = lane >> 4;

    f32x4 acc0 = {0.f, 0.f, 0.f, 0.f};
    f32x4 acc1 = {0.f, 0.f, 0.f, 0.f};
    f32x4 acc2 = {0.f, 0.f, 0.f, 0.f};
    f32x4 acc3 = {0.f, 0.f, 0.f, 0.f};

    const short* xr = X + (size_t)(wave * 64 + lr) * HID + g * 8 + k0;
    const float* wr = W + (size_t)(nbase + lr) * HID + g * 8 + k0;

    #pragma unroll 4
    for (int kc = 0; kc < 512; kc += 32) {
        float4 w0 = *reinterpret_cast<const float4*>(wr + kc);
        float4 w1 = *reinterpret_cast<const float4*>(wr + kc + 4);
        short8 bb = pack8(w0, w1);
        short8 a0 = *reinterpret_cast<const short8*>(xr + kc);
        short8 a1 = *reinterpret_cast<const short8*>(xr + (size_t)16 * HID + kc);
        short8 a2 = *reinterpret_cast<const short8*>(xr + (size_t)32 * HID + kc);
        short8 a3 = *reinterpret_cast<const short8*>(xr + (size_t)48 * HID + kc);
        acc0 = MFMA(a0, bb, acc0);
        acc1 = MFMA(a1, bb, acc1);
        acc2 = MFMA(a2, bb, acc2);
        acc3 = MFMA(a3, bb, acc3);
    }
    #define STACC(accv, f) do { \
        Y[(size_t)(wave * 64 + (f) * 16 + (g << 2) + 0) * HID + nbase + lr] = accv[0]; \
        Y[(size_t)(wave * 64 + (f) * 16 + (g << 2) + 1) * HID + nbase + lr] = accv[1]; \
        Y[(size_t)(wave * 64 + (f) * 16 + (g << 2) + 2) * HID + nbase + lr] = accv[2]; \
        Y[(size_t)(wave * 64 + (f) * 16 + (g << 2) + 3) * HID + nbase + lr] = accv[3]; \
    } while (0)
    STACC(acc0, 0); STACC(acc1, 1); STACC(acc2, 2); STACC(acc3, 3);
    #undef STACC
}

// -------- sum the 4 K-slice partials ------------------------------------
__global__ __launch_bounds__(256) void merge4_kernel(
        const float* __restrict__ Yp,
        float* __restrict__ Y0, float* __restrict__ Y1, float* __restrict__ Y2) {
    int mat = blockIdx.x >> 8;
    int blk = blockIdx.x & 255;
    float* Y = (mat == 0) ? Y0 : (mat == 1) ? Y1 : Y2;
    const float* P = Yp + (size_t)mat * 4 * MATSZ;
    int idx = blk * 1024 + threadIdx.x * 4;
    float4 a = *reinterpret_cast<const float4*>(P + idx);
    float4 b = *reinterpret_cast<const float4*>(P + MATSZ + idx);
    float4 c = *reinterpret_cast<const float4*>(P + 2 * MATSZ + idx);
    float4 d = *reinterpret_cast<const float4*>(P + 3 * MATSZ + idx);
    float4 s;
    s.x = a.x + b.x + c.x + d.x;
    s.y = a.y + b.y + c.y + d.y;
    s.z = a.z + b.z + c.z + d.z;
    s.w = a.w + b.w + c.w + d.w;
    *reinterpret_cast<float4*>(Y + idx) = s;
}

// ---------------- fused attention, 8 blocks per (b,h) -------------------
// blockIdx.x = bh*8 + split. 256 threads = 4 waves; per 64-pos tile, wave w
// owns positions [w*16, w*16+16). V path: coalesced float4 -> regs (counted
// vmcnt) -> bf16 ds_write into per-wave [16][VP] u16 slab (double-buffered);
// DSW for tile t+1 sits a full tile after its loads. K regs 2 tiles ahead.
// LDS ~17.9KB -> 8 blocks/CU = 32 waves/CU at 64 VGPR.
__global__ __launch_bounds__(256, 4) void attn_kernel(
        const float* __restrict__ q,
        const float* __restrict__ knew, const float* __restrict__ vnew,
        const float* __restrict__ pastK, const float* __restrict__ pastV,
        float* __restrict__ parts) {
    __shared__ __align__(16) unsigned char lds_raw[4 * WSLAB];
    __shared__ float s_m[4][16];
    __shared__ float s_l[4][16];

    int bid = blockIdx.x;
    int bh = bid >> 3, split = bid & 7;
    int b = bh >> 5, h = bh & 31;
    int wave = threadIdx.x >> 6, lane = threadIdx.x & 63;
    int lq = lane & 15, g = lane >> 4;
    int vrow = lane >> 4;        // row-within-4 for V loads/stores
    int vcol = (lane & 15) * 4;  // d-offset for V loads/stores

    unsigned short* vbuf0 = (unsigned short*)(lds_raw + wave * WSLAB);
    unsigned short* vbuf1 = vbuf0 + 16 * VP;

    // Q fragments (B operand of swapped QK^T), pre-scaled by log2(e)/8
    const float* qp = q + (size_t)(b * NS + lq) * HID + h * HD + g * 8;
    short8 qf0, qf1;
    {
        float4 a0 = *reinterpret_cast<const float4*>(qp);
        float4 a1 = *reinterpret_cast<const float4*>(qp + 4);
        float4 a2 = *reinterpret_cast<const float4*>(qp + 32);
        float4 a3 = *reinterpret_cast<const float4*>(qp + 36);
        qf0 = pack8s(a0, a1, QSCALE);
        qf1 = pack8s(a2, a3, QSCALE);
    }

    f32x4 o0 = {0.f, 0.f, 0.f, 0.f};
    f32x4 o1 = {0.f, 0.f, 0.f, 0.f};
    f32x4 o2 = {0.f, 0.f, 0.f, 0.f};
    f32x4 o3 = {0.f, 0.f, 0.f, 0.f};
    float m = -__builtin_inff(), lsum = 0.0f;

    const float* ksplit = pastK + (size_t)bh * PAST * HD + (size_t)split * 512 * HD;
    const float* vsplit = pastV + (size_t)bh * PAST * HD + (size_t)split * 512 * HD;

    #define ISSUE_K(T, A, Bv, C, D) do { \
        const float* kr_ = ksplit + (size_t)((T) * 64 + wave * 16 + lq) * HD + (g << 3); \
        A  = *reinterpret_cast<const float4*>(kr_); \
        Bv = *reinterpret_cast<const float4*>(kr_ + 4); \
        C  = *reinterpret_cast<const float4*>(kr_ + 32); \
        D  = *reinterpret_cast<const float4*>(kr_ + 36); \
    } while (0)

    #define ISSUE_V(T, V0, V1, V2, V3) do { \
        const float* vr_ = vsplit + (size_t)((T) * 64 + wave * 16) * HD; \
        V0 = *reinterpret_cast<const float4*>(vr_ + (0 * 4 + vrow) * HD + vcol); \
        V1 = *reinterpret_cast<const float4*>(vr_ + (1 * 4 + vrow) * HD + vcol); \
        V2 = *reinterpret_cast<const float4*>(vr_ + (2 * 4 + vrow) * HD + vcol); \
        V3 = *reinterpret_cast<const float4*>(vr_ + (3 * 4 + vrow) * HD + vcol); \
    } while (0)

    // convert + store staged V regs into slab (b64 stores, bf16)
    #define DSW(V0, V1, V2, V3, BUFP) do { \
        unsigned short* ds_ = (BUFP); \
        *reinterpret_cast<short4v*>(ds_ + (0 * 4 + vrow) * VP + vcol) = pack4(V0); \
        *reinterpret_cast<short4v*>(ds_ + (1 * 4 + vrow) * VP + vcol) = pack4(V1); \
        *reinterpret_cast<short4v*>(ds_ + (2 * 4 + vrow) * VP + vcol) = pack4(V2); \
        *reinterpret_cast<short4v*>(ds_ + (3 * 4 + vrow) * VP + vcol) = pack4(V3); \
    } while (0)

    #define QKSM(A, Bv, C, D, PF) do { \
        short8 af0 = pack8(A, Bv); \
        short8 af1 = pack8(C, D); \
        f32x4 sv = {0.f, 0.f, 0.f, 0.f}; \
        sv = MFMA(af0, qf0, sv); \
        sv = MFMA(af1, qf1, sv); \
        float tmax = fmaxf(fmaxf(sv[0], sv[1]), fmaxf(sv[2], sv[3])); \
        tmax = fmaxf(tmax, __shfl_xor(tmax, 16)); \
        tmax = fmaxf(tmax, __shfl_xor(tmax, 32)); \
        float mn = fmaxf(m, tmax); \
        float alpha = exp2f(m - mn); \
        float e0 = exp2f(sv[0] - mn); \
        float e1 = exp2f(sv[1] - mn); \
        float e2 = exp2f(sv[2] - mn); \
        float e3 = exp2f(sv[3] - mn); \
        float rsum = e0 + e1 + e2 + e3; \
        rsum += __shfl_xor(rsum, 16); \
        rsum += __shfl_xor(rsum, 32); \
        lsum = lsum * alpha + rsum; \
        m = mn; \
        o0 *= alpha; o1 *= alpha; o2 *= alpha; o3 *= alpha; \
        PF[0] = f2bf(e0); PF[1] = f2bf(e1); PF[2] = f2bf(e2); PF[3] = f2bf(e3); \
        PF[4] = 0; PF[5] = 0; PF[6] = 0; PF[7] = 0; \
    } while (0)

    // PV from slab: vf[j] = V[pos=4g+j][dcol] (bf16 direct; banks conflict-free)
    #define PV(BUFP, PF) do { \
        const unsigned short* vc = (BUFP) + (g << 2) * VP; \
        short8 vf; \
        vf[4] = 0; vf[5] = 0; vf[6] = 0; vf[7] = 0; \
        vf[0] = (short)vc[0 * VP + lq];      vf[1] = (short)vc[1 * VP + lq]; \
        vf[2] = (short)vc[2 * VP + lq];      vf[3] = (short)vc[3 * VP + lq]; \
        o0 = MFMA(vf, PF, o0); \
        vf[0] = (short)vc[0 * VP + 16 + lq]; vf[1] = (short)vc[1 * VP + 16 + lq]; \
        vf[2] = (short)vc[2 * VP + 16 + lq]; vf[3] = (short)vc[3 * VP + 16 + lq]; \
        o1 = MFMA(vf, PF, o1); \
        vf[0] = (short)vc[0 * VP + 32 + lq]; vf[1] = (short)vc[1 * VP + 32 + lq]; \
        vf[2] = (short)vc[2 * VP + 32 + lq]; vf[3] = (short)vc[3 * VP + 32 + lq]; \
        o2 = MFMA(vf, PF, o2); \
        vf[0] = (short)vc[0 * VP + 48 + lq]; vf[1] = (short)vc[1 * VP + 48 + lq]; \
        vf[2] = (short)vc[2 * VP + 48 + lq]; vf[3] = (short)vc[3 * VP + 48 + lq]; \
        o3 = MFMA(vf, PF, o3); \
    } while (0)

    float4 kA0, kA1, kA2, kA3, kB0, kB1, kB2, kB3;
    float4 vA0, vA1, vA2, vA3, vB0, vB1, vB2, vB3;

    // prologue: tile0 -> kA/buf0; tile1 -> kB/vB(regs)
    ISSUE_V(0, vA0, vA1, vA2, vA3);
    ISSUE_K(0, kA0, kA1, kA2, kA3);
    DSW(vA0, vA1, vA2, vA3, vbuf0);
    ISSUE_V(1, vB0, vB1, vB2, vB3);
    ISSUE_K(1, kB0, kB1, kB2, kB3);

    #pragma unroll 1
    for (int tt = 0; tt < 4; ++tt) {
        // tile 2tt (kA, buf0); stage tile 2tt+1's V (full tile since issue)
        short8 pfE;
        QKSM(kA0, kA1, kA2, kA3, pfE);
        DSW(vB0, vB1, vB2, vB3, vbuf1);
        if (tt < 3) {
            ISSUE_V(2 * tt + 2, vA0, vA1, vA2, vA3);
            ISSUE_K(2 * tt + 2, kA0, kA1, kA2, kA3);
        }
        PV(vbuf0, pfE);
        // tile 2tt+1 (kB, buf1)
        short8 pfO;
        QKSM(kB0, kB1, kB2, kB3, pfO);
        if (tt < 3) {
            DSW(vA0, vA1, vA2, vA3, vbuf0);
            ISSUE_V(2 * tt + 3, vB0, vB1, vB2, vB3);
            ISSUE_K(2 * tt + 3, kB0, kB1, kB2, kB3);
        }
        PV(vbuf1, pfO);
    }
    #undef PV
    #undef QKSM
    #undef DSW
    #undef ISSUE_V
    #undef ISSUE_K

    // ---- the 16 new tokens (wave 0 of split-0 block) ----
    if (split == 0 && wave == 0) {
        const float* kr = knew + (size_t)(b * NS + lq) * HID + h * HD + g * 8;
        float4 ka = *reinterpret_cast<const float4*>(kr);
        float4 kb2 = *reinterpret_cast<const float4*>(kr + 4);
        float4 kc2 = *reinterpret_cast<const float4*>(kr + 32);
        float4 kd2 = *reinterpret_cast<const float4*>(kr + 36);
        short8 af0 = pack8(ka, kb2);
        short8 af1 = pack8(kc2, kd2);
        f32x4 sv = {0.f, 0.f, 0.f, 0.f};
        sv = MFMA(af0, qf0, sv);
        sv = MFMA(af1, qf1, sv);

        float tmax = fmaxf(fmaxf(sv[0], sv[1]), fmaxf(sv[2], sv[3]));
        tmax = fmaxf(tmax, __shfl_xor(tmax, 16));
        tmax = fmaxf(tmax, __shfl_xor(tmax, 32));
        float mn = fmaxf(m, tmax);
        float alpha = exp2f(m - mn);
        float e0 = exp2f(sv[0] - mn);
        float e1 = exp2f(sv[1] - mn);
        float e2 = exp2f(sv[2] - mn);
        float e3 = exp2f(sv[3] - mn);
        float rsum = e0 + e1 + e2 + e3;
        rsum += __shfl_xor(rsum, 16);
        rsum += __shfl_xor(rsum, 32);
        lsum = lsum * alpha + rsum;
        m = mn;
        o0 *= alpha; o1 *= alpha; o2 *= alpha; o3 *= alpha;

        short8 pfT;
        pfT[0] = f2bf(e0); pfT[1] = f2bf(e1); pfT[2] = f2bf(e2); pfT[3] = f2bf(e3);
        pfT[4] = 0; pfT[5] = 0; pfT[6] = 0; pfT[7] = 0;

        const float* vt2 = vnew + (size_t)(b * NS) * HID + h * HD;
        #define LOADVT(dst, dcol) do { \
            dst[0] = f2bf(vt2[(size_t)((g << 2) + 0) * HID + (dcol)]); \
            dst[1] = f2bf(vt2[(size_t)((g << 2) + 1) * HID + (dcol)]); \
            dst[2] = f2bf(vt2[(size_t)((g << 2) + 2) * HID + (dcol)]); \
            dst[3] = f2bf(vt2[(size_t)((g << 2) + 3) * HID + (dcol)]); \
            dst[4] = 0; dst[5] = 0; dst[6] = 0; dst[7] = 0; \
        } while (0)
        short8 vv0, vv1, vv2, vv3;
        LOADVT(vv0, lq); LOADVT(vv1, 16 + lq); LOADVT(vv2, 32 + lq); LOADVT(vv3, 48 + lq);
        #undef LOADVT
        o0 = MFMA(vv0, pfT, o0);
        o1 = MFMA(vv1, pfT, o1);
        o2 = MFMA(vv2, pfT, o2);
        o3 = MFMA(vv3, pfT, o3);
    }

    // ---- merge the 4 wave-partials; reuse the per-wave slab as [16 q][64 d] ----
    float* so_w = (float*)(lds_raw + wave * WSLAB);
    #define STO(ov, dt) do { \
        so_w[lq * 64 + (dt) * 16 + (g << 2) + 0] = ov[0]; \
        so_w[lq * 64 + (dt) * 16 + (g << 2) + 1] = ov[1]; \
        so_w[lq * 64 + (dt) * 16 + (g << 2) + 2] = ov[2]; \
        so_w[lq * 64 + (dt) * 16 + (g << 2) + 3] = ov[3]; \
    } while (0)
    STO(o0, 0); STO(o1, 1); STO(o2, 2); STO(o3, 3);
    #undef STO
    if (g == 0) { s_m[wave][lq] = m; s_l[wave][lq] = lsum; }
    __syncthreads();

    if (wave == 0) {
        float M = fmaxf(fmaxf(s_m[0][lq], s_m[1][lq]), fmaxf(s_m[2][lq], s_m[3][lq]));
        float aw0 = exp2f(s_m[0][lq] - M);
        float aw1 = exp2f(s_m[1][lq] - M);
        float aw2 = exp2f(s_m[2][lq] - M);
        float aw3 = exp2f(s_m[3][lq] - M);
        float L = aw0 * s_l[0][lq] + aw1 * s_l[1][lq] + aw2 * s_l[2][lq] + aw3 * s_l[3][lq];
        const float* so0 = (const float*)(lds_raw + 0 * WSLAB);
        const float* so1 = (const float*)(lds_raw + 1 * WSLAB);
        const float* so2 = (const float*)(lds_raw + 2 * WSLAB);
        const float* so3 = (const float*)(lds_raw + 3 * WSLAB);
        float* pbase = parts + (size_t)bid * PART_STRIDE;
        if (g == 0) { pbase[lq] = M; pbase[16 + lq] = L; }
        for (int dd = 0; dd < 16; ++dd) {
            int di = g * 16 + dd;
            float v = aw0 * so0[lq * 64 + di] + aw1 * so1[lq * 64 + di] +
                      aw2 * so2[lq * 64 + di] + aw3 * so3[lq * 64 + di];
            pbase[32 + lq * 64 + di] = v;
        }
    }
}

// ---------------- merge the 8 split-partials per (b,h) -------------------
__global__ __launch_bounds__(256) void merge_kernel(const float* __restrict__ parts,
                                                    short* __restrict__ attnb) {
    int bh = blockIdx.x;            // b*32 + h
    int tid = threadIdx.x;
    int qi = tid >> 4, ds = (tid & 15) * 4;
    const float* pb0 = parts + (size_t)(bh * NSPLIT) * PART_STRIDE;

    float M = -__builtin_inff();
    #pragma unroll
    for (int i = 0; i < NSPLIT; ++i)
        M = fmaxf(M, pb0[(size_t)i * PART_STRIDE + qi]);

    float aw0, aw1, aw2, aw3, aw4, aw5, aw6, aw7;
    float L = 0.f;
    #define AW(i, awv) do { \
        awv = exp2f(pb0[(size_t)(i) * PART_STRIDE + qi] - M); \
        L += awv * pb0[(size_t)(i) * PART_STRIDE + 16 + qi]; \
    } while (0)
    AW(0, aw0); AW(1, aw1); AW(2, aw2); AW(3, aw3);
    AW(4, aw4); AW(5, aw5); AW(6, aw6); AW(7, aw7);
    #undef AW
    float inv = 1.0f / L;

    int b = bh >> 5, h = bh & 31;
    int base = 32 + qi * 64 + ds;
    short4v o;
    #pragma unroll
    for (int r = 0; r < 4; ++r) {
        float v = aw0 * pb0[(size_t)0 * PART_STRIDE + base + r]
                + aw1 * pb0[(size_t)1 * PART_STRIDE + base + r]
                + aw2 * pb0[(size_t)2 * PART_STRIDE + base + r]
                + aw3 * pb0[(size_t)3 * PART_STRIDE + base + r]
                + aw4 * pb0[(size_t)4 * PART_STRIDE + base + r]
                + aw5 * pb0[(size_t)5 * PART_STRIDE + base + r]
                + aw6 * pb0[(size_t)6 * PART_STRIDE + base + r]
                + aw7 * pb0[(size_t)7 * PART_STRIDE + base + r];
        o[r] = f2bf(v * inv);
    }
    *reinterpret_cast<short4v*>(attnb + (size_t)(b * NS + qi) * HID + h * HD + ds) = o;
}

extern "C" void kernel_launch(void* const* d_in, const int* in_sizes, int n_in,
                              void* d_out, int out_size, void* d_ws, size_t ws_size,
                              hipStream_t stream) {
    const float* hs     = (const float*)d_in[0];
    const float* past_k = (const float*)d_in[1];
    const float* past_v = (const float*)d_in[2];
    const float* wq     = (const float*)d_in[3];
    const float* wk     = (const float*)d_in[4];
    const float* wv     = (const float*)d_in[5];
    const float* wo     = (const float*)d_in[6];
    float* out = (float*)d_out;

    float* qb    = (float*)d_ws;                  // 128x2048 f32
    float* kn    = qb + MATSZ;                    // 128x2048 f32
    float* vn    = kn + MATSZ;                    // 128x2048 f32
    short* hsb   = (short*)(vn + MATSZ);          // 128x2048 bf16
    short* attnb = hsb + MATSZ;                   // 128x2048 bf16
    float* parts = (float*)(attnb + MATSZ);       // 2048 * PART_STRIDE f32
    float* qkvp  = parts + 2048 * PART_STRIDE;    // 3*4*MATSZ f32 partials
    float* op    = qkvp + 3 * 4 * MATSZ;          // 4*MATSZ f32 partials

    cvt_kernel<<<256, 256, 0, stream>>>(hs, hsb);
    proj_kernel<<<1536, 128, 0, stream>>>(hsb, wq, wk, wv, qkvp);
    merge4_kernel<<<768, 256, 0, stream>>>(qkvp, qb, kn, vn);
    attn_kernel<<<256 * NSPLIT, 256, 0, stream>>>(qb, kn, vn, past_k, past_v, parts);
    merge_kernel<<<256, 256, 0, stream>>>(parts, attnb);
    proj_kernel<<<512, 128, 0, stream>>>(attnb, wo, wo, wo, op);
    merge4_kernel<<<256, 256, 0, stream>>>(op, out, out, out);
}